// Round 26
// baseline (128.838 us; speedup 1.0000x reference)
//
#include <hip/hip_runtime.h>
#include <math.h>

#define N_NODES 50000
#define IN_CH   128
#define HEADS   4
#define HID     64
#define NEDGE   800000
#define EPS     1e-6f
#define LN_EPS  1e-5f
#define PAD     48                   // padded CSR row stride
#define MTILES  (N_NODES / 16)       // 3125 16-node M-tiles
#define SEGS    100                  // edge segments
#define SEG     8000                 // edges per segment (multiple of 4)
#define NG      12500                // node u32-groups (4 packed u8 counters each)

typedef __attribute__((ext_vector_type(8))) _Float16 f16x8;
typedef __attribute__((ext_vector_type(4))) float    f32x4;

// ---- cross-lane reduce helpers --------------------------------------
#define DPP_ADD_F(p, ctrl) \
    p += __int_as_float(__builtin_amdgcn_update_dpp(0, __float_as_int(p), ctrl, 0xF, 0xF, true))
#define REDUCE16_DPP(p) { DPP_ADD_F(p,0xB1); DPP_ADD_F(p,0x4E); \
                          DPP_ADD_F(p,0x141); DPP_ADD_F(p,0x140); }
#define REDUCE4_DPP(p)  { DPP_ADD_F(p,0xB1); DPP_ADD_F(p,0x4E); }
#define REDUCE64(p) { REDUCE16_DPP(p); p += __shfl_xor(p,16); p += __shfl_xor(p,32); }

// ---------------- kernel A: segment histogram + local ranks ----------
// LDS atomics (bank-speed) replace the ~12G/s global-atomic wall.
// Packed u8x4 counters: 50KB LDS covers all 50K nodes. The atomic
// return IS the edge's local rank within (segment, row).
__global__ __launch_bounds__(512) void cnt_kernel(const int* __restrict__ ei,
                                                  unsigned* __restrict__ cnt,
                                                  unsigned char* __restrict__ lrank) {
    __shared__ unsigned lc[NG];                  // 50KB
    for (int i = threadIdx.x; i < NG; i += 512) lc[i] = 0u;
    __syncthreads();
    int base = blockIdx.x * SEG;
#pragma unroll 1
    for (int it = 0; it < SEG / 512 + 1; ++it) { // 16 iters
        int el = it * 512 + threadIdx.x;
        if (el < SEG) {
            int e = base + el;
            int n = ei[e];                       // row
            unsigned sh  = 8u * (n & 3);
            unsigned old = atomicAdd(&lc[n >> 2], 1u << sh);
            lrank[e] = (unsigned char)((old >> sh) & 0xFFu);   // coalesced
        }
    }
    __syncthreads();
    for (int i = threadIdx.x; i < NG; i += 512)
        cnt[blockIdx.x * NG + i] = lc[i];        // coalesced 50KB
}

// ---------------- kernel B: per-node prefix over segments + deg ------
// In-place exclusive prefix (SWAR u8x4: deg<=48 -> no byte carries).
// 4-deep manual pipeline keeps 4 loads in flight per lane.
__global__ __launch_bounds__(256) void prefix_kernel(unsigned* __restrict__ cnt,
                                                     unsigned* __restrict__ deg4) {
    int g = blockIdx.x * 256 + threadIdx.x;
    if (g >= NG) return;
    unsigned run = 0u;
#pragma unroll 1
    for (int s = 0; s < SEGS; s += 4) {
        unsigned c0 = cnt[(s + 0) * NG + g];
        unsigned c1 = cnt[(s + 1) * NG + g];
        unsigned c2 = cnt[(s + 2) * NG + g];
        unsigned c3 = cnt[(s + 3) * NG + g];
        cnt[(s + 0) * NG + g] = run; run += c0;
        cnt[(s + 1) * NG + g] = run; run += c1;
        cnt[(s + 2) * NG + g] = run; run += c2;
        cnt[(s + 3) * NG + g] = run; run += c3;
    }
    deg4[g] = run;                               // packed u8 degrees
}

// ---------------- kernel C: atomic-free CSR fill ---------------------
// pos = row*PAD + sbase[seg][row] + lrank[e]; injective within row.
// Pure loads + fire-and-forget NT scatter: no RMW anywhere.
__global__ __launch_bounds__(256) void fill_kernel(const int* __restrict__ ei,
                                                   const unsigned* __restrict__ sbase,
                                                   const unsigned char* __restrict__ lrank,
                                                   int* __restrict__ csr_col) {
    int t = blockIdx.x * 256 + threadIdx.x;
    if (t >= NEDGE / 4) return;
    int s = t / (SEG / 4);                       // segment (2000 quads each)
    int4 r = ((const int4*)ei)[t];
    int4 c = ((const int4*)(ei + NEDGE))[t];
    unsigned lr4 = ((const unsigned*)lrank)[t];

    int n0 = r.x, n1 = r.y, n2 = r.z, n3 = r.w;
    int sb0 = (sbase[s * NG + (n0 >> 2)] >> (8 * (n0 & 3))) & 0xFF;
    int sb1 = (sbase[s * NG + (n1 >> 2)] >> (8 * (n1 & 3))) & 0xFF;
    int sb2 = (sbase[s * NG + (n2 >> 2)] >> (8 * (n2 & 3))) & 0xFF;
    int sb3 = (sbase[s * NG + (n3 >> 2)] >> (8 * (n3 & 3))) & 0xFF;
    int sl0 = sb0 + ((lr4 >> 0)  & 0xFF);
    int sl1 = sb1 + ((lr4 >> 8)  & 0xFF);
    int sl2 = sb2 + ((lr4 >> 16) & 0xFF);
    int sl3 = sb3 + ((lr4 >> 24) & 0xFF);
    if (sl0 < PAD) __builtin_nontemporal_store(c.x, &csr_col[n0 * PAD + sl0]);
    if (sl1 < PAD) __builtin_nontemporal_store(c.y, &csr_col[n1 * PAD + sl1]);
    if (sl2 < PAD) __builtin_nontemporal_store(c.z, &csr_col[n2 * PAD + sl2]);
    if (sl3 < PAD) __builtin_nontemporal_store(c.w, &csr_col[n3 * PAD + sl3]);
}

// ---------------- kernel D: MFMA h GEMM (R24-proven, standalone) -----
__global__ __launch_bounds__(256, 4) void h_kernel(const float* __restrict__ x,
                                                   const float* __restrict__ lin_w,
                                                   float* __restrict__ h,
                                                   float* __restrict__ inv_hn) {
    int lane = threadIdx.x & 63;
    int wave = threadIdx.x >> 6;
    int mt = blockIdx.x * 4 + wave;              // M-tile id
    if (mt >= MTILES) return;

    int node0 = mt * 16;
    int mrow  = lane & 15;                       // A row / D col
    int kg    = lane >> 4;                       // k-group 0..3
    const float4* xp = (const float4*)x;
    const float4* w4 = (const float4*)lin_w;

    f16x8 A[4];
#pragma unroll
    for (int s = 0; s < 4; ++s) {
        float4 u0 = xp[(node0 + mrow) * 32 + s * 8 + kg * 2];
        float4 u1 = xp[(node0 + mrow) * 32 + s * 8 + kg * 2 + 1];
        f16x8 a;
        a[0] = (_Float16)u0.x; a[1] = (_Float16)u0.y;
        a[2] = (_Float16)u0.z; a[3] = (_Float16)u0.w;
        a[4] = (_Float16)u1.x; a[5] = (_Float16)u1.y;
        a[6] = (_Float16)u1.z; a[7] = (_Float16)u1.w;
        A[s] = a;
    }

#pragma unroll
    for (int nt = 0; nt < 4; ++nt) {             // 16-channel block = head nt
        f32x4 C = {0.f, 0.f, 0.f, 0.f};
#pragma unroll
        for (int s = 0; s < 4; ++s) {
            int wrow = nt * 16 + mrow;
            float4 u0 = w4[wrow * 32 + s * 8 + kg * 2];
            float4 u1 = w4[wrow * 32 + s * 8 + kg * 2 + 1];
            f16x8 b;
            b[0] = (_Float16)u0.x; b[1] = (_Float16)u0.y;
            b[2] = (_Float16)u0.z; b[3] = (_Float16)u0.w;
            b[4] = (_Float16)u1.x; b[5] = (_Float16)u1.y;
            b[6] = (_Float16)u1.z; b[7] = (_Float16)u1.w;
            C = __builtin_amdgcn_mfma_f32_16x16x32_f16(A[s], b, C, 0, 0, 0);
        }
        float ss0 = C[0] * C[0], ss1 = C[1] * C[1];
        float ss2 = C[2] * C[2], ss3 = C[3] * C[3];
#pragma unroll
        for (int rr = 0; rr < 4; ++rr)
            h[(node0 + 4 * kg + rr) * HID + nt * 16 + mrow] = C[rr];
        REDUCE16_DPP(ss0); REDUCE16_DPP(ss1);
        REDUCE16_DPP(ss2); REDUCE16_DPP(ss3);
        if (mrow == 0) {
            inv_hn[(node0 + 4 * kg + 0) * HEADS + nt] = 1.0f / fmaxf(sqrtf(ss0), 1e-12f);
            inv_hn[(node0 + 4 * kg + 1) * HEADS + nt] = 1.0f / fmaxf(sqrtf(ss1), 1e-12f);
            inv_hn[(node0 + 4 * kg + 2) * HEADS + nt] = 1.0f / fmaxf(sqrtf(ss2), 1e-12f);
            inv_hn[(node0 + 4 * kg + 3) * HEADS + nt] = 1.0f / fmaxf(sqrtf(ss3), 1e-12f);
        }
    }
}

// ---------------- kernel E: gather (float4 pack, 4 edges/instr) ------
// R23-proven; deg now read as u8.
__global__ __launch_bounds__(256, 4) void gather_final(const unsigned char* __restrict__ deg8,
                                                       const int* __restrict__ csr_col,
                                                       const float* __restrict__ h,
                                                       const float* __restrict__ inv_hn,
                                                       const float* __restrict__ bcos_w,
                                                       const float* __restrict__ gamma,
                                                       const float* __restrict__ beta,
                                                       float* __restrict__ y) {
    __shared__ float4 wt4[16][65];               // padded staging
    __shared__ float rowbuf[4][HID];
    __shared__ float ivw[HID], gm[HID], bt[HID];

    for (int i = threadIdx.x; i < HID * (HID / 4); i += 256) {
        int j = i >> 4, k4 = i & 15;
        wt4[k4][j] = ((const float4*)bcos_w)[i];
    }
    if (threadIdx.x < HID) {
        gm[threadIdx.x] = gamma[threadIdx.x];
        bt[threadIdx.x] = beta[threadIdx.x];
    }
    __syncthreads();
    if (threadIdx.x < HID) {                     // inv_w from staged wt4
        float ss = 0.f;
#pragma unroll
        for (int k4 = 0; k4 < 16; ++k4) {
            float4 q = wt4[k4][threadIdx.x];
            ss += q.x * q.x + q.y * q.y + q.z * q.z + q.w * q.w;
        }
        ivw[threadIdx.x] = 1.0f / fmaxf(sqrtf(ss), 1e-12f);
    }
    __syncthreads();

    int grp    = threadIdx.x >> 6;
    int lane   = threadIdx.x & 63;
    int e_slot = lane >> 4;                      // edge slot 0..3
    int ch4    = lane & 15;                      // channel-quad index
    int hd     = ch4 >> 2;                       // head of my quad

    const float4* h4 = (const float4*)h;

    for (int g = blockIdx.x; g < N_NODES / 4; g += gridDim.x) {
        int node = g * 4 + grp;
        float4 hq  = h4[node * 16 + ch4];
        float  ihr = inv_hn[node * HEADS + hd];
        float4 hrs4 = make_float4(hq.x * ihr, hq.y * ihr, hq.z * ihr, hq.w * ihr);
        int dg    = __builtin_amdgcn_readfirstlane(min((int)deg8[node], PAD));
        int start = node * PAD;

        float4 acc = make_float4(0.f, 0.f, 0.f, 0.f);
#pragma unroll 1
        for (int bb = 0; bb < dg; bb += 16) {
            int   cc[4];
            float4 hh[4];
            float ii[4];
#pragma unroll
            for (int s = 0; s < 4; ++s) {
                int e = bb + s * 4 + e_slot;               // per-lane edge id
                int ix = (e < dg) ? e : dg - 1;            // clamp
                cc[s] = csr_col[start + ix];
            }
#pragma unroll
            for (int s = 0; s < 4; ++s) hh[s] = h4[cc[s] * 16 + ch4];
#pragma unroll
            for (int s = 0; s < 4; ++s) ii[s] = inv_hn[cc[s] * HEADS + hd];
#pragma unroll
            for (int s = 0; s < 4; ++s) {
                float p = hh[s].x * hrs4.x + hh[s].y * hrs4.y
                        + hh[s].z * hrs4.z + hh[s].w * hrs4.w;
                REDUCE4_DPP(p);                            // 16-ch head dot
                float sc = fminf(fmaxf(p * ii[s], EPS), 1.0f);  // B_EXP=2
                int e = bb + s * 4 + e_slot;
                sc = (e < dg) ? sc : 0.0f;
                acc.x = fmaf(hh[s].x, sc, acc.x);
                acc.y = fmaf(hh[s].y, sc, acc.y);
                acc.z = fmaf(hh[s].z, sc, acc.z);
                acc.w = fmaf(hh[s].w, sc, acc.w);
            }
        }
        // fold the 4 edge-slots (lanes xor 16, 32)
        acc.x += __shfl_xor(acc.x, 16); acc.x += __shfl_xor(acc.x, 32);
        acc.y += __shfl_xor(acc.y, 16); acc.y += __shfl_xor(acc.y, 32);
        acc.z += __shfl_xor(acc.z, 16); acc.z += __shfl_xor(acc.z, 32);
        acc.w += __shfl_xor(acc.w, 16); acc.w += __shfl_xor(acc.w, 32);

        if (lane < 16) ((float4*)rowbuf[grp])[ch4] = acc;
        float o = rowbuf[grp][lane];

        // ---- fused epilogue: bcos linear + layernorm ----
        float ss = o * o;
        REDUCE64(ss);
        float inv_no = 1.0f / fmaxf(sqrtf(ss), 1e-12f);

        const float4* rb4 = (const float4*)rowbuf[grp];
        float lin = 0.f;
#pragma unroll
        for (int k4 = 0; k4 < 16; ++k4) {
            float4 a  = rb4[k4];
            float4 wv = wt4[k4][lane];
            lin += a.x * wv.x + a.y * wv.y + a.z * wv.z + a.w * wv.w;
        }

        float c2v = lin * inv_no * ivw[lane];
        c2v = fminf(fmaxf(c2v, EPS), 1.0f);
        float ob = lin * c2v;                // B_EXP=2 -> cos2**1

        float mu = ob;
        REDUCE64(mu);
        mu *= (1.0f / 64.0f);
        float d = ob - mu;
        float var = d * d;
        REDUCE64(var);
        var *= (1.0f / 64.0f);
        float r = rsqrtf(var + LN_EPS);
        y[node * HID + lane] = d * r * gm[lane] + bt[lane];
    }
}

// ---------------------------------------------------------------------
extern "C" void kernel_launch(void* const* d_in, const int* in_sizes, int n_in,
                              void* d_out, int out_size, void* d_ws, size_t ws_size,
                              hipStream_t stream) {
    const float* x      = (const float*)d_in[0];
    const int*   ei     = (const int*)d_in[1];
    const float* lin_w  = (const float*)d_in[2];
    const float* bcos_w = (const float*)d_in[3];
    const float* gamma  = (const float*)d_in[4];
    const float* beta   = (const float*)d_in[5];
    float*       y      = (float*)d_out;

    // workspace (23.25 MB):
    //   h [0, 12.8MB)  -- ALIASED during CSR build by:
    //       cnt   [0, 5MB)      (SEGS*NG u32; becomes sbase after prefix)
    //       lrank [5MB, 5.8MB)  (NEDGE u8)
    //   (cnt/lrank dead before h_kernel writes h)
    float* h        = (float*)d_ws;                         // N*64 f (12.8MB)
    unsigned* cnt   = (unsigned*)d_ws;                      // 5MB (aliased)
    unsigned char* lrank = (unsigned char*)d_ws + (size_t)SEGS * NG * 4; // 0.8MB
    float* inv_hn   = h + (size_t)N_NODES * HID;            // 0.8MB
    unsigned* deg4  = (unsigned*)(inv_hn + (size_t)N_NODES * HEADS); // 50KB
    int*   csr_col  = (int*)(deg4 + NG);                    // 9.6MB

    cnt_kernel<<<SEGS, 512, 0, stream>>>(ei, cnt, lrank);

    prefix_kernel<<<(NG + 255) / 256, 256, 0, stream>>>(cnt, deg4);

    fill_kernel<<<(NEDGE / 4 + 255) / 256, 256, 0, stream>>>(ei, cnt, lrank, csr_col);

    h_kernel<<<(MTILES + 3) / 4, 256, 0, stream>>>(x, lin_w, h, inv_hn);

    gather_final<<<2048, 256, 0, stream>>>((const unsigned char*)deg4, csr_col,
                                           h, inv_hn, bcos_w, gamma, beta, y);
}

// Round 27
// 120.010 us; speedup vs baseline: 1.0736x; 1.0736x over previous
//
#include <hip/hip_runtime.h>
#include <math.h>

#define N_NODES 50000
#define IN_CH   128
#define HEADS   4
#define HID     64
#define NEDGE   800000
#define EPS     1e-6f
#define LN_EPS  1e-5f
#define PAD     48                   // padded CSR row stride
#define MTILES  (N_NODES / 16)       // 3125 16-node M-tiles
#define SEGS    100                  // edge segments
#define SEG     8000                 // edges per segment
#define NG      12500                // node u32-groups (4 packed u8 counters)

typedef __attribute__((ext_vector_type(8))) _Float16 f16x8;
typedef __attribute__((ext_vector_type(4))) float    f32x4;

// ---- cross-lane reduce helpers --------------------------------------
#define DPP_ADD_F(p, ctrl) \
    p += __int_as_float(__builtin_amdgcn_update_dpp(0, __float_as_int(p), ctrl, 0xF, 0xF, true))
#define REDUCE16_DPP(p) { DPP_ADD_F(p,0xB1); DPP_ADD_F(p,0x4E); \
                          DPP_ADD_F(p,0x141); DPP_ADD_F(p,0x140); }
#define REDUCE4_DPP(p)  { DPP_ADD_F(p,0xB1); DPP_ADD_F(p,0x4E); }
#define REDUCE64(p) { REDUCE16_DPP(p); p += __shfl_xor(p,16); p += __shfl_xor(p,32); }

// ---------------- kernel A: segment histogram + local ranks ----------
__global__ __launch_bounds__(512) void cnt_kernel(const int* __restrict__ ei,
                                                  unsigned* __restrict__ cnt,
                                                  unsigned char* __restrict__ lrank) {
    __shared__ unsigned lc[NG];                  // 50KB
    for (int i = threadIdx.x; i < NG; i += 512) lc[i] = 0u;
    __syncthreads();
    int base = blockIdx.x * SEG;
#pragma unroll 1
    for (int it = 0; it < SEG / 512 + 1; ++it) {
        int el = it * 512 + threadIdx.x;
        if (el < SEG) {
            int e = base + el;
            int n = ei[e];
            unsigned sh  = 8u * (n & 3);
            unsigned old = atomicAdd(&lc[n >> 2], 1u << sh);
            lrank[e] = (unsigned char)((old >> sh) & 0xFFu);
        }
    }
    __syncthreads();
    for (int i = threadIdx.x; i < NG; i += 512)
        cnt[blockIdx.x * NG + i] = lc[i];
}

// ---------------- kernel B: per-node prefix over segments + deg ------
__global__ __launch_bounds__(256) void prefix_kernel(unsigned* __restrict__ cnt,
                                                     unsigned* __restrict__ deg4) {
    int g = blockIdx.x * 256 + threadIdx.x;
    if (g >= NG) return;
    unsigned run = 0u;
#pragma unroll 1
    for (int s = 0; s < SEGS; s += 4) {
        unsigned c0 = cnt[(s + 0) * NG + g];
        unsigned c1 = cnt[(s + 1) * NG + g];
        unsigned c2 = cnt[(s + 2) * NG + g];
        unsigned c3 = cnt[(s + 3) * NG + g];
        cnt[(s + 0) * NG + g] = run; run += c0;
        cnt[(s + 1) * NG + g] = run; run += c1;
        cnt[(s + 2) * NG + g] = run; run += c2;
        cnt[(s + 3) * NG + g] = run; run += c3;
    }
    deg4[g] = run;
}

// ---- shared MFMA GEMM body (one 16-node M-tile per wave) ------------
__device__ __forceinline__ void gemm_mtile(int mt, const float* __restrict__ x,
                                           const float* __restrict__ lin_w,
                                           float* __restrict__ h,
                                           float* __restrict__ inv_hn, int lane) {
    int node0 = mt * 16;
    int mrow  = lane & 15;
    int kg    = lane >> 4;
    const float4* xp = (const float4*)x;
    const float4* w4 = (const float4*)lin_w;

    f16x8 A[4];
#pragma unroll
    for (int s = 0; s < 4; ++s) {
        float4 u0 = xp[(node0 + mrow) * 32 + s * 8 + kg * 2];
        float4 u1 = xp[(node0 + mrow) * 32 + s * 8 + kg * 2 + 1];
        f16x8 a;
        a[0] = (_Float16)u0.x; a[1] = (_Float16)u0.y;
        a[2] = (_Float16)u0.z; a[3] = (_Float16)u0.w;
        a[4] = (_Float16)u1.x; a[5] = (_Float16)u1.y;
        a[6] = (_Float16)u1.z; a[7] = (_Float16)u1.w;
        A[s] = a;
    }
#pragma unroll
    for (int nt = 0; nt < 4; ++nt) {
        f32x4 C = {0.f, 0.f, 0.f, 0.f};
#pragma unroll
        for (int s = 0; s < 4; ++s) {
            int wrow = nt * 16 + mrow;
            float4 u0 = w4[wrow * 32 + s * 8 + kg * 2];
            float4 u1 = w4[wrow * 32 + s * 8 + kg * 2 + 1];
            f16x8 b;
            b[0] = (_Float16)u0.x; b[1] = (_Float16)u0.y;
            b[2] = (_Float16)u0.z; b[3] = (_Float16)u0.w;
            b[4] = (_Float16)u1.x; b[5] = (_Float16)u1.y;
            b[6] = (_Float16)u1.z; b[7] = (_Float16)u1.w;
            C = __builtin_amdgcn_mfma_f32_16x16x32_f16(A[s], b, C, 0, 0, 0);
        }
        float ss0 = C[0] * C[0], ss1 = C[1] * C[1];
        float ss2 = C[2] * C[2], ss3 = C[3] * C[3];
#pragma unroll
        for (int rr = 0; rr < 4; ++rr)
            h[(node0 + 4 * kg + rr) * HID + nt * 16 + mrow] = C[rr];
        REDUCE16_DPP(ss0); REDUCE16_DPP(ss1);
        REDUCE16_DPP(ss2); REDUCE16_DPP(ss3);
        if (mrow == 0) {
            inv_hn[(node0 + 4 * kg + 0) * HEADS + nt] = 1.0f / fmaxf(sqrtf(ss0), 1e-12f);
            inv_hn[(node0 + 4 * kg + 1) * HEADS + nt] = 1.0f / fmaxf(sqrtf(ss1), 1e-12f);
            inv_hn[(node0 + 4 * kg + 2) * HEADS + nt] = 1.0f / fmaxf(sqrtf(ss2), 1e-12f);
            inv_hn[(node0 + 4 * kg + 3) * HEADS + nt] = 1.0f / fmaxf(sqrtf(ss3), 1e-12f);
        }
    }
}

// ---------------- kernel C+D fused: atomic-free fill + MFMA GEMM -----
// 782 blocks: each thread scatters 1 edge-quad (pure loads + NT store),
// each wave computes 1 M-tile. Scatter latency hides under the GEMM.
__global__ __launch_bounds__(256, 4) void fill_h_kernel(const float* __restrict__ x,
                                                        const float* __restrict__ lin_w,
                                                        float* __restrict__ h,
                                                        float* __restrict__ inv_hn,
                                                        const int* __restrict__ ei,
                                                        const unsigned* __restrict__ sbase,
                                                        const unsigned char* __restrict__ lrank,
                                                        int* __restrict__ csr_col) {
    int lane = threadIdx.x & 63;
    int wave = threadIdx.x >> 6;

    int t = blockIdx.x * 256 + threadIdx.x;
    bool have_e = (t < NEDGE / 4);
    int4 r, c; unsigned lr4 = 0;
    int sb0 = 0, sb1 = 0, sb2 = 0, sb3 = 0;
    if (have_e) {
        r   = ((const int4*)ei)[t];
        c   = ((const int4*)(ei + NEDGE))[t];
        lr4 = ((const unsigned*)lrank)[t];
        int s = t / (SEG / 4);
        sb0 = (sbase[s * NG + (r.x >> 2)] >> (8 * (r.x & 3))) & 0xFF;
        sb1 = (sbase[s * NG + (r.y >> 2)] >> (8 * (r.y & 3))) & 0xFF;
        sb2 = (sbase[s * NG + (r.z >> 2)] >> (8 * (r.z & 3))) & 0xFF;
        sb3 = (sbase[s * NG + (r.w >> 2)] >> (8 * (r.w & 3))) & 0xFF;
    }

    int mt = blockIdx.x * 4 + wave;
    if (mt < MTILES) gemm_mtile(mt, x, lin_w, h, inv_hn, lane);

    if (have_e) {                         // loads long since landed
        int sl0 = sb0 + ((lr4 >> 0)  & 0xFF);
        int sl1 = sb1 + ((lr4 >> 8)  & 0xFF);
        int sl2 = sb2 + ((lr4 >> 16) & 0xFF);
        int sl3 = sb3 + ((lr4 >> 24) & 0xFF);
        if (sl0 < PAD) __builtin_nontemporal_store(c.x, &csr_col[r.x * PAD + sl0]);
        if (sl1 < PAD) __builtin_nontemporal_store(c.y, &csr_col[r.y * PAD + sl1]);
        if (sl2 < PAD) __builtin_nontemporal_store(c.z, &csr_col[r.z * PAD + sl2]);
        if (sl3 < PAD) __builtin_nontemporal_store(c.w, &csr_col[r.w * PAD + sl3]);
    }
}

// ---- fallback split kernels (aliased-workspace path) ----------------
__global__ __launch_bounds__(256) void fill_kernel(const int* __restrict__ ei,
                                                   const unsigned* __restrict__ sbase,
                                                   const unsigned char* __restrict__ lrank,
                                                   int* __restrict__ csr_col) {
    int t = blockIdx.x * 256 + threadIdx.x;
    if (t >= NEDGE / 4) return;
    int s = t / (SEG / 4);
    int4 r = ((const int4*)ei)[t];
    int4 c = ((const int4*)(ei + NEDGE))[t];
    unsigned lr4 = ((const unsigned*)lrank)[t];
    int sl0 = ((sbase[s * NG + (r.x >> 2)] >> (8 * (r.x & 3))) & 0xFF) + ((lr4 >> 0)  & 0xFF);
    int sl1 = ((sbase[s * NG + (r.y >> 2)] >> (8 * (r.y & 3))) & 0xFF) + ((lr4 >> 8)  & 0xFF);
    int sl2 = ((sbase[s * NG + (r.z >> 2)] >> (8 * (r.z & 3))) & 0xFF) + ((lr4 >> 16) & 0xFF);
    int sl3 = ((sbase[s * NG + (r.w >> 2)] >> (8 * (r.w & 3))) & 0xFF) + ((lr4 >> 24) & 0xFF);
    if (sl0 < PAD) __builtin_nontemporal_store(c.x, &csr_col[r.x * PAD + sl0]);
    if (sl1 < PAD) __builtin_nontemporal_store(c.y, &csr_col[r.y * PAD + sl1]);
    if (sl2 < PAD) __builtin_nontemporal_store(c.z, &csr_col[r.z * PAD + sl2]);
    if (sl3 < PAD) __builtin_nontemporal_store(c.w, &csr_col[r.w * PAD + sl3]);
}

__global__ __launch_bounds__(256, 4) void h_kernel(const float* __restrict__ x,
                                                   const float* __restrict__ lin_w,
                                                   float* __restrict__ h,
                                                   float* __restrict__ inv_hn) {
    int mt = blockIdx.x * 4 + (threadIdx.x >> 6);
    if (mt < MTILES) gemm_mtile(mt, x, lin_w, h, inv_hn, threadIdx.x & 63);
}

// ---------------- kernel E: gather (float4 pack, 4 edges/instr) ------
__global__ __launch_bounds__(256, 4) void gather_final(const unsigned char* __restrict__ deg8,
                                                       const int* __restrict__ csr_col,
                                                       const float* __restrict__ h,
                                                       const float* __restrict__ inv_hn,
                                                       const float* __restrict__ bcos_w,
                                                       const float* __restrict__ gamma,
                                                       const float* __restrict__ beta,
                                                       float* __restrict__ y) {
    __shared__ float4 wt4[16][65];
    __shared__ float rowbuf[4][HID];
    __shared__ float ivw[HID], gm[HID], bt[HID];

    for (int i = threadIdx.x; i < HID * (HID / 4); i += 256) {
        int j = i >> 4, k4 = i & 15;
        wt4[k4][j] = ((const float4*)bcos_w)[i];
    }
    if (threadIdx.x < HID) {
        gm[threadIdx.x] = gamma[threadIdx.x];
        bt[threadIdx.x] = beta[threadIdx.x];
    }
    __syncthreads();
    if (threadIdx.x < HID) {
        float ss = 0.f;
#pragma unroll
        for (int k4 = 0; k4 < 16; ++k4) {
            float4 q = wt4[k4][threadIdx.x];
            ss += q.x * q.x + q.y * q.y + q.z * q.z + q.w * q.w;
        }
        ivw[threadIdx.x] = 1.0f / fmaxf(sqrtf(ss), 1e-12f);
    }
    __syncthreads();

    int grp    = threadIdx.x >> 6;
    int lane   = threadIdx.x & 63;
    int e_slot = lane >> 4;
    int ch4    = lane & 15;
    int hd     = ch4 >> 2;

    const float4* h4 = (const float4*)h;

    for (int g = blockIdx.x; g < N_NODES / 4; g += gridDim.x) {
        int node = g * 4 + grp;
        float4 hq  = h4[node * 16 + ch4];
        float  ihr = inv_hn[node * HEADS + hd];
        float4 hrs4 = make_float4(hq.x * ihr, hq.y * ihr, hq.z * ihr, hq.w * ihr);
        int dg    = __builtin_amdgcn_readfirstlane(min((int)deg8[node], PAD));
        int start = node * PAD;

        float4 acc = make_float4(0.f, 0.f, 0.f, 0.f);
#pragma unroll 1
        for (int bb = 0; bb < dg; bb += 16) {
            int   cc[4];
            float4 hh[4];
            float ii[4];
#pragma unroll
            for (int s = 0; s < 4; ++s) {
                int e = bb + s * 4 + e_slot;
                int ix = (e < dg) ? e : dg - 1;
                cc[s] = csr_col[start + ix];
            }
#pragma unroll
            for (int s = 0; s < 4; ++s) hh[s] = h4[cc[s] * 16 + ch4];
#pragma unroll
            for (int s = 0; s < 4; ++s) ii[s] = inv_hn[cc[s] * HEADS + hd];
#pragma unroll
            for (int s = 0; s < 4; ++s) {
                float p = hh[s].x * hrs4.x + hh[s].y * hrs4.y
                        + hh[s].z * hrs4.z + hh[s].w * hrs4.w;
                REDUCE4_DPP(p);
                float sc = fminf(fmaxf(p * ii[s], EPS), 1.0f);  // B_EXP=2
                int e = bb + s * 4 + e_slot;
                sc = (e < dg) ? sc : 0.0f;
                acc.x = fmaf(hh[s].x, sc, acc.x);
                acc.y = fmaf(hh[s].y, sc, acc.y);
                acc.z = fmaf(hh[s].z, sc, acc.z);
                acc.w = fmaf(hh[s].w, sc, acc.w);
            }
        }
        acc.x += __shfl_xor(acc.x, 16); acc.x += __shfl_xor(acc.x, 32);
        acc.y += __shfl_xor(acc.y, 16); acc.y += __shfl_xor(acc.y, 32);
        acc.z += __shfl_xor(acc.z, 16); acc.z += __shfl_xor(acc.z, 32);
        acc.w += __shfl_xor(acc.w, 16); acc.w += __shfl_xor(acc.w, 32);

        if (lane < 16) ((float4*)rowbuf[grp])[ch4] = acc;
        float o = rowbuf[grp][lane];

        float ss = o * o;
        REDUCE64(ss);
        float inv_no = 1.0f / fmaxf(sqrtf(ss), 1e-12f);

        const float4* rb4 = (const float4*)rowbuf[grp];
        float lin = 0.f;
#pragma unroll
        for (int k4 = 0; k4 < 16; ++k4) {
            float4 a  = rb4[k4];
            float4 wv = wt4[k4][lane];
            lin += a.x * wv.x + a.y * wv.y + a.z * wv.z + a.w * wv.w;
        }

        float c2v = lin * inv_no * ivw[lane];
        c2v = fminf(fmaxf(c2v, EPS), 1.0f);
        float ob = lin * c2v;

        float mu = ob;
        REDUCE64(mu);
        mu *= (1.0f / 64.0f);
        float d = ob - mu;
        float var = d * d;
        REDUCE64(var);
        var *= (1.0f / 64.0f);
        float r = rsqrtf(var + LN_EPS);
        y[node * HID + lane] = d * r * gm[lane] + bt[lane];
    }
}

// ---------------------------------------------------------------------
extern "C" void kernel_launch(void* const* d_in, const int* in_sizes, int n_in,
                              void* d_out, int out_size, void* d_ws, size_t ws_size,
                              hipStream_t stream) {
    const float* x      = (const float*)d_in[0];
    const int*   ei     = (const int*)d_in[1];
    const float* lin_w  = (const float*)d_in[2];
    const float* bcos_w = (const float*)d_in[3];
    const float* gamma  = (const float*)d_in[4];
    const float* beta   = (const float*)d_in[5];
    float*       y      = (float*)d_out;

    const size_t CNT_B   = (size_t)SEGS * NG * 4;      // 5MB
    const size_t LRANK_B = NEDGE;                      // 0.8MB
    const size_t H_B     = (size_t)N_NODES * HID * 4;  // 12.8MB
    const size_t INV_B   = (size_t)N_NODES * HEADS * 4;// 0.8MB
    const size_t DEG_B   = NG * 4;                     // 50KB
    const size_t CSR_B   = (size_t)N_NODES * PAD * 4;  // 9.6MB

    if (ws_size >= CNT_B + LRANK_B + H_B + INV_B + DEG_B + CSR_B) {
        // ---- fused path (no aliasing): 4 dispatches ----
        char* p = (char*)d_ws;
        unsigned* cnt        = (unsigned*)p;            p += CNT_B;
        unsigned char* lrank = (unsigned char*)p;       p += LRANK_B;
        float* h             = (float*)p;               p += H_B;
        float* inv_hn        = (float*)p;               p += INV_B;
        unsigned* deg4       = (unsigned*)p;            p += DEG_B;
        int* csr_col         = (int*)p;

        cnt_kernel<<<SEGS, 512, 0, stream>>>(ei, cnt, lrank);
        prefix_kernel<<<(NG + 255) / 256, 256, 0, stream>>>(cnt, deg4);
        fill_h_kernel<<<(MTILES + 3) / 4, 256, 0, stream>>>(x, lin_w, h, inv_hn,
                                                            ei, cnt, lrank, csr_col);
        gather_final<<<2048, 256, 0, stream>>>((const unsigned char*)deg4, csr_col,
                                               h, inv_hn, bcos_w, gamma, beta, y);
    } else {
        // ---- fallback (R26 aliased layout): 5 dispatches ----
        float* h             = (float*)d_ws;            // 12.8MB (aliased below)
        unsigned* cnt        = (unsigned*)d_ws;         // 5MB
        unsigned char* lrank = (unsigned char*)d_ws + CNT_B; // 0.8MB
        float* inv_hn        = h + (size_t)N_NODES * HID;
        unsigned* deg4       = (unsigned*)(inv_hn + (size_t)N_NODES * HEADS);
        int* csr_col         = (int*)(deg4 + NG);

        cnt_kernel<<<SEGS, 512, 0, stream>>>(ei, cnt, lrank);
        prefix_kernel<<<(NG + 255) / 256, 256, 0, stream>>>(cnt, deg4);
        fill_kernel<<<(NEDGE / 4 + 255) / 256, 256, 0, stream>>>(ei, cnt, lrank, csr_col);
        h_kernel<<<(MTILES + 3) / 4, 256, 0, stream>>>(x, lin_w, h, inv_hn);
        gather_final<<<2048, 256, 0, stream>>>((const unsigned char*)deg4, csr_col,
                                               h, inv_hn, bcos_w, gamma, beta, y);
    }
}